// Round 1
// baseline (113.769 us; speedup 1.0000x reference)
//
#include <hip/hip_runtime.h>
#include <hip/hip_bf16.h>
#include <stdint.h>

#define BB 16
#define NN 1024
#define MM 1024
#define DD 128
#define VERY_NEG (-1e30f)

using bf16x8 = __attribute__((ext_vector_type(8))) short;
using f32x4  = __attribute__((ext_vector_type(4))) float;

__device__ inline unsigned short f2bf(float f) {
    union { float f; uint32_t u; } cv; cv.f = f;
    uint32_t u = cv.u;
    return (unsigned short)((u + 0x7FFFu + ((u >> 16) & 1u)) >> 16);
}

// ---- prep: per-row dots (a = q.w_q, c = m.w_m) + bf16 casts (qp = q*w_qm, mb = m) ----
__global__ void prep_rows(const float* __restrict__ q, const float* __restrict__ mem,
                          const float* __restrict__ wq, const float* __restrict__ wm,
                          const float* __restrict__ wqm,
                          float* __restrict__ a, float* __restrict__ c,
                          unsigned short* __restrict__ qp, unsigned short* __restrict__ mb)
{
    int wave = (blockIdx.x * 256 + threadIdx.x) >> 6;
    int lane = threadIdx.x & 63;
    bool is_q = wave < BB * NN;
    int row = is_q ? wave : wave - BB * NN;
    const float* src = (is_q ? q : mem) + (size_t)row * DD;
    const float* wd  = is_q ? wq : wm;
    float2 v  = *(const float2*)(src + lane * 2);
    float2 w2 = *(const float2*)(wd + lane * 2);
    float dot = v.x * w2.x + v.y * w2.y;
    #pragma unroll
    for (int o = 32; o; o >>= 1) dot += __shfl_xor(dot, o);
    if (lane == 0) (is_q ? a : c)[row] = dot;
    float2 s2 = v;
    if (is_q) { float2 wv = *(const float2*)(wqm + lane * 2); s2.x *= wv.x; s2.y *= wv.y; }
    ushort2 o2; o2.x = f2bf(s2.x); o2.y = f2bf(s2.y);
    *(ushort2*)((is_q ? qp : mb) + (size_t)row * DD + lane * 2) = o2;
}

// ---- transpose memory into mt[b][d][m] (bf16) for the PV B-operand ----
__global__ void transpose_mem(const float* __restrict__ mem, unsigned short* __restrict__ mt)
{
    __shared__ unsigned short t[64][72];
    int bid = blockIdx.x;
    int dt = bid & 1, mtile = (bid >> 1) & 15, b = bid >> 5;
    int d0 = dt * 64, m0 = mtile * 64;
    int tid = threadIdx.x;
    int cc = tid & 63, rr = tid >> 6;
    #pragma unroll
    for (int r = 0; r < 64; r += 4) {
        float v = mem[((size_t)b * MM + m0 + r + rr) * DD + d0 + cc];
        t[cc][r + rr] = f2bf(v);
    }
    __syncthreads();
    #pragma unroll
    for (int r = 0; r < 64; r += 4) {
        mt[((size_t)b * DD + d0 + r + rr) * MM + m0 + cc] = t[r + rr][cc];
    }
}

// ---- flash main: 1 wave/block, 16 q-rows per wave, iterate M in 32-chunks ----
__global__ __launch_bounds__(64) void flash_fwd(
    const unsigned short* __restrict__ qp, const unsigned short* __restrict__ mb,
    const unsigned short* __restrict__ mt,
    const float* __restrict__ a, const float* __restrict__ c,
    const int* __restrict__ qmask, const int* __restrict__ mmask,
    float* __restrict__ out1, float* __restrict__ rowmax)
{
    __shared__ unsigned short pl[16][40];
    int lane = threadIdx.x & 63;
    int g = lane >> 4, qi = lane & 15;
    int b = blockIdx.x >> 6, nt = blockIdx.x & 63;
    int n0 = nt * 16;

    // Q' B-frags: lane l elem j = Q'[col=qi][k = kc*32 + g*8 + j]
    const unsigned short* qpb = qp + ((size_t)b * NN + n0) * DD;
    bf16x8 qf[4];
    #pragma unroll
    for (int kc = 0; kc < 4; kc++)
        qf[kc] = *(const bf16x8*)(qpb + qi * DD + kc * 32 + g * 8);

    float a_q = a[b * NN + n0 + qi];
    int   qm  = qmask[b * NN + n0 + qi];

    float m_run = -INFINITY, l_run = 0.f;
    f32x4 o[8];
    #pragma unroll
    for (int d2 = 0; d2 < 8; d2++) o[d2] = (f32x4){0.f, 0.f, 0.f, 0.f};

    const unsigned short* mbB = mb + (size_t)b * MM * DD;
    const unsigned short* mtB = mt + (size_t)b * DD * MM;
    const float* cB = c + b * MM;
    const int* mmB  = mmask + b * MM;

    for (int m0 = 0; m0 < MM; m0 += 32) {
        // S^T tiles (16m x 16q), two per chunk
        f32x4 st[2];
        st[0] = (f32x4){0,0,0,0}; st[1] = (f32x4){0,0,0,0};
        #pragma unroll
        for (int t = 0; t < 2; t++) {
            const unsigned short* arow = mbB + (size_t)(m0 + t * 16 + qi) * DD + g * 8;
            #pragma unroll
            for (int kc = 0; kc < 4; kc++) {
                bf16x8 af = *(const bf16x8*)(arow + kc * 32);
                st[t] = __builtin_amdgcn_mfma_f32_16x16x32_bf16(af, qf[kc], st[t], 0, 0, 0);
            }
        }
        // biases + mask; S^T acc layout: lane(g,qi) reg i -> m = m0 + t*16 + g*4 + i, q = qi
        float sv[2][4];
        float cmax = -INFINITY;
        #pragma unroll
        for (int t = 0; t < 2; t++) {
            float4 cv = *(const float4*)(cB + m0 + t * 16 + g * 4);
            int4   mv = *(const int4*)(mmB + m0 + t * 16 + g * 4);
            float cc4[4] = {cv.x, cv.y, cv.z, cv.w};
            int   mk4[4] = {mv.x, mv.y, mv.z, mv.w};
            #pragma unroll
            for (int i = 0; i < 4; i++) {
                float s = st[t][i] + a_q + cc4[i];
                if (!(qm && mk4[i])) s += VERY_NEG;   // f32 absorption == reference semantics
                sv[t][i] = s;
                cmax = fmaxf(cmax, s);
            }
        }
        cmax = fmaxf(cmax, __shfl_xor(cmax, 16));
        cmax = fmaxf(cmax, __shfl_xor(cmax, 32));
        float m_new = fmaxf(m_run, cmax);
        float alpha = __expf(m_run - m_new);
        float psum = 0.f;
        #pragma unroll
        for (int t = 0; t < 2; t++) {
            unsigned short pe[4];
            #pragma unroll
            for (int i = 0; i < 4; i++) {
                float p = __expf(sv[t][i] - m_new);
                psum += p;
                pe[i] = f2bf(p);
            }
            ushort4 pw; pw.x = pe[0]; pw.y = pe[1]; pw.z = pe[2]; pw.w = pe[3];
            *(ushort4*)(&pl[qi][t * 16 + g * 4]) = pw;   // P[q][mlocal]
        }
        psum += __shfl_xor(psum, 16);
        psum += __shfl_xor(psum, 32);
        l_run = l_run * alpha + psum;
        m_run = m_new;

        // per-output-row alpha (rows q = g*4+i in O acc layout)
        float aL[4];
        #pragma unroll
        for (int i = 0; i < 4; i++) aL[i] = __shfl(alpha, g * 4 + i);

        __builtin_amdgcn_sched_barrier(0);
        // PV: A-frag P[row=qi][k = g*8+j] from LDS; B-frag Mem[m][d] from mt
        bf16x8 pa = *(const bf16x8*)(&pl[qi][g * 8]);
        #pragma unroll
        for (int d2 = 0; d2 < 8; d2++) {
            bf16x8 vf = *(const bf16x8*)(mtB + (size_t)(d2 * 16 + qi) * MM + m0 + g * 8);
            f32x4 oo = o[d2];
            #pragma unroll
            for (int i = 0; i < 4; i++) oo[i] *= aL[i];
            o[d2] = __builtin_amdgcn_mfma_f32_16x16x32_bf16(pa, vf, oo, 0, 0, 0);
        }
    }

    if (lane < 16) rowmax[b * NN + n0 + qi] = m_run;

    float inv[4];
    #pragma unroll
    for (int i = 0; i < 4; i++) inv[i] = 1.f / __shfl(l_run, g * 4 + i);

    #pragma unroll
    for (int d2 = 0; d2 < 8; d2++) {
        #pragma unroll
        for (int i = 0; i < 4; i++) {
            out1[((size_t)b * NN + n0 + g * 4 + i) * DD + d2 * 16 + qi] = o[d2][i] * inv[i];
        }
    }
}

// ---- m2q: softmax over rowmax (per batch), weighted sum of query ----
__global__ void m2q_kernel(const float* __restrict__ rowmax, const float* __restrict__ query,
                           float* __restrict__ m2q)
{
    int b = blockIdx.x;
    int tid = threadIdx.x;
    int lane = tid & 63, wid = tid >> 6;
    __shared__ float pe[NN];
    __shared__ float red[8];
    __shared__ float half1[128];
    float4 rv = *(const float4*)(rowmax + b * NN + tid * 4);
    float mx = fmaxf(fmaxf(rv.x, rv.y), fmaxf(rv.z, rv.w));
    #pragma unroll
    for (int o = 32; o; o >>= 1) mx = fmaxf(mx, __shfl_xor(mx, o));
    if (lane == 0) red[wid] = mx;
    __syncthreads();
    mx = fmaxf(fmaxf(red[0], red[1]), fmaxf(red[2], red[3]));
    float e0 = __expf(rv.x - mx), e1 = __expf(rv.y - mx);
    float e2 = __expf(rv.z - mx), e3 = __expf(rv.w - mx);
    pe[tid * 4 + 0] = e0; pe[tid * 4 + 1] = e1;
    pe[tid * 4 + 2] = e2; pe[tid * 4 + 3] = e3;
    float ls = e0 + e1 + e2 + e3;
    #pragma unroll
    for (int o = 32; o; o >>= 1) ls += __shfl_xor(ls, o);
    if (lane == 0) red[4 + wid] = ls;
    __syncthreads();
    float Z = red[4] + red[5] + red[6] + red[7];

    int d = tid & 127, h = tid >> 7;
    float acc = 0.f;
    const float* qb = query + ((size_t)b * NN + h * 512) * DD + d;
    #pragma unroll 8
    for (int n = 0; n < 512; n++) acc += pe[h * 512 + n] * qb[(size_t)n * DD];
    if (h) half1[d] = acc;
    __syncthreads();
    if (!h) m2q[b * DD + d] = (acc + half1[d]) / Z;
}

// ---- broadcast m2q to out2[b][n][d] ----
__global__ void bcast_kernel(const float* __restrict__ m2q, float4* __restrict__ out2)
{
    int i = blockIdx.x * 256 + threadIdx.x;   // 524288 float4s
    int b = i >> 15;                          // N*D/4 = 32768
    int d4 = i & 31;                          // D/4 = 32
    out2[i] = ((const float4*)m2q)[(b << 5) + d4];
}

extern "C" void kernel_launch(void* const* d_in, const int* in_sizes, int n_in,
                              void* d_out, int out_size, void* d_ws, size_t ws_size,
                              hipStream_t stream)
{
    const float* query  = (const float*)d_in[0];
    const float* memory = (const float*)d_in[1];
    const float* w_q    = (const float*)d_in[2];
    const float* w_m    = (const float*)d_in[3];
    const float* w_qm   = (const float*)d_in[4];
    const int*   qmask  = (const int*)d_in[5];
    const int*   mmask  = (const int*)d_in[6];
    float* out1 = (float*)d_out;
    float* out2 = out1 + (size_t)BB * NN * DD;

    char* ws = (char*)d_ws;
    float* a      = (float*)ws;                 // B*N
    float* c      = a + BB * NN;                // B*M
    float* rowmax = c + BB * MM;                // B*N
    float* m2q    = rowmax + BB * NN;           // B*D
    unsigned short* qp = (unsigned short*)(ws + (1 << 20));
    unsigned short* mb = qp + (size_t)BB * NN * DD;
    unsigned short* mt = mb + (size_t)BB * MM * DD;

    prep_rows<<<dim3((BB * NN + BB * MM) / 4), 256, 0, stream>>>(query, memory, w_q, w_m, w_qm, a, c, qp, mb);
    transpose_mem<<<dim3(BB * (MM / 64) * (DD / 64)), 256, 0, stream>>>(memory, mt);
    flash_fwd<<<dim3(BB * 64), 64, 0, stream>>>(qp, mb, mt, a, c, qmask, mmask, out1, rowmax);
    m2q_kernel<<<dim3(BB), 256, 0, stream>>>(rowmax, query, m2q);
    bcast_kernel<<<dim3(2048), 256, 0, stream>>>(m2q, (float4*)out2);
}

// Round 2
// 91.377 us; speedup vs baseline: 1.2450x; 1.2450x over previous
//
#include <hip/hip_runtime.h>
#include <hip/hip_bf16.h>
#include <stdint.h>

#define BB 16
#define NN 1024
#define MM 1024
#define DD 128
#define VERY_NEG (-1e30f)
#define NSPLIT 4          // waves per flash block; each wave covers MM/NSPLIT m-values

using bf16x8 = __attribute__((ext_vector_type(8))) short;
using f32x4  = __attribute__((ext_vector_type(4))) float;

__device__ inline unsigned short f2bf(float f) {
    union { float f; uint32_t u; } cv; cv.f = f;
    uint32_t u = cv.u;
    return (unsigned short)((u + 0x7FFFu + ((u >> 16) & 1u)) >> 16);
}

// ---- prep: per-row dots (a = q.w_q, c = m.w_m) + bf16 casts (qp = q*w_qm, mb = m) ----
__global__ void prep_rows(const float* __restrict__ q, const float* __restrict__ mem,
                          const float* __restrict__ wq, const float* __restrict__ wm,
                          const float* __restrict__ wqm,
                          float* __restrict__ a, float* __restrict__ c,
                          unsigned short* __restrict__ qp, unsigned short* __restrict__ mb)
{
    int wave = (blockIdx.x * 256 + threadIdx.x) >> 6;
    int lane = threadIdx.x & 63;
    bool is_q = wave < BB * NN;
    int row = is_q ? wave : wave - BB * NN;
    const float* src = (is_q ? q : mem) + (size_t)row * DD;
    const float* wd  = is_q ? wq : wm;
    float2 v  = *(const float2*)(src + lane * 2);
    float2 w2 = *(const float2*)(wd + lane * 2);
    float dot = v.x * w2.x + v.y * w2.y;
    #pragma unroll
    for (int o = 32; o; o >>= 1) dot += __shfl_xor(dot, o);
    if (lane == 0) (is_q ? a : c)[row] = dot;
    float2 s2 = v;
    if (is_q) { float2 wv = *(const float2*)(wqm + lane * 2); s2.x *= wv.x; s2.y *= wv.y; }
    ushort2 o2; o2.x = f2bf(s2.x); o2.y = f2bf(s2.y);
    *(ushort2*)((is_q ? qp : mb) + (size_t)row * DD + lane * 2) = o2;
}

// ---- transpose memory into mt[b][d][m] (bf16) for the PV B-operand ----
__global__ void transpose_mem(const float* __restrict__ mem, unsigned short* __restrict__ mt)
{
    __shared__ unsigned short t[64][72];
    int bid = blockIdx.x;
    int dt = bid & 1, mtile = (bid >> 1) & 15, b = bid >> 5;
    int d0 = dt * 64, m0 = mtile * 64;
    int tid = threadIdx.x;
    int cc = tid & 63, rr = tid >> 6;
    #pragma unroll
    for (int r = 0; r < 64; r += 4) {
        float v = mem[((size_t)b * MM + m0 + r + rr) * DD + d0 + cc];
        t[cc][r + rr] = f2bf(v);
    }
    __syncthreads();
    #pragma unroll
    for (int r = 0; r < 64; r += 4) {
        mt[((size_t)b * DD + d0 + r + rr) * MM + m0 + cc] = t[r + rr][cc];
    }
}

// ---- flash main: 4 waves/block, same 16 q-rows, M-split across waves, LDS merge ----
__global__ __launch_bounds__(256) void flash_fwd(
    const unsigned short* __restrict__ qp, const unsigned short* __restrict__ mb,
    const unsigned short* __restrict__ mt,
    const float* __restrict__ a, const float* __restrict__ c,
    const int* __restrict__ qmask, const int* __restrict__ mmask,
    float* __restrict__ out1, float* __restrict__ rowmax)
{
    __shared__ unsigned short pl[NSPLIT][16][40];
    __shared__ float Obuf[NSPLIT][16][130];   // 130-pad: conflict-free scatter across g
    __shared__ float mlb[NSPLIT][16][2];

    int tid = threadIdx.x;
    int w = tid >> 6, lane = tid & 63;
    int g = lane >> 4, qi = lane & 15;
    int b = blockIdx.x >> 6, nt = blockIdx.x & 63;
    int n0 = nt * 16;

    // Q' B-frags: lane l elem j = Q'[col=qi][k = kc*32 + g*8 + j]
    const unsigned short* qpb = qp + ((size_t)b * NN + n0) * DD;
    bf16x8 qf[4];
    #pragma unroll
    for (int kc = 0; kc < 4; kc++)
        qf[kc] = *(const bf16x8*)(qpb + qi * DD + kc * 32 + g * 8);

    float a_q = a[b * NN + n0 + qi];
    int   qm  = qmask[b * NN + n0 + qi];

    float m_run = -INFINITY, l_run = 0.f;
    f32x4 o[8];
    #pragma unroll
    for (int d2 = 0; d2 < 8; d2++) o[d2] = (f32x4){0.f, 0.f, 0.f, 0.f};

    const unsigned short* mbB = mb + (size_t)b * MM * DD;
    const unsigned short* mtB = mt + (size_t)b * DD * MM;
    const float* cB = c + b * MM;
    const int* mmB  = mmask + b * MM;

    int mbase = w * (MM / NSPLIT);
    for (int mc = 0; mc < MM / NSPLIT; mc += 32) {
        int m0 = mbase + mc;
        // S^T tiles (16m x 16q), two per chunk
        f32x4 st[2];
        st[0] = (f32x4){0,0,0,0}; st[1] = (f32x4){0,0,0,0};
        #pragma unroll
        for (int t = 0; t < 2; t++) {
            const unsigned short* arow = mbB + (size_t)(m0 + t * 16 + qi) * DD + g * 8;
            #pragma unroll
            for (int kc = 0; kc < 4; kc++) {
                bf16x8 af = *(const bf16x8*)(arow + kc * 32);
                st[t] = __builtin_amdgcn_mfma_f32_16x16x32_bf16(af, qf[kc], st[t], 0, 0, 0);
            }
        }
        // biases + mask; S^T acc layout: lane(g,qi) reg i -> m = m0 + t*16 + g*4 + i, q = qi
        float sv[2][4];
        float cmax = -INFINITY;
        #pragma unroll
        for (int t = 0; t < 2; t++) {
            float4 cv = *(const float4*)(cB + m0 + t * 16 + g * 4);
            int4   mv = *(const int4*)(mmB + m0 + t * 16 + g * 4);
            float cc4[4] = {cv.x, cv.y, cv.z, cv.w};
            int   mk4[4] = {mv.x, mv.y, mv.z, mv.w};
            #pragma unroll
            for (int i = 0; i < 4; i++) {
                float s = st[t][i] + a_q + cc4[i];
                if (!(qm && mk4[i])) s += VERY_NEG;   // f32 absorption == reference semantics
                sv[t][i] = s;
                cmax = fmaxf(cmax, s);
            }
        }
        cmax = fmaxf(cmax, __shfl_xor(cmax, 16));
        cmax = fmaxf(cmax, __shfl_xor(cmax, 32));
        float m_new = fmaxf(m_run, cmax);
        float alpha = __expf(m_run - m_new);
        float psum = 0.f;
        #pragma unroll
        for (int t = 0; t < 2; t++) {
            unsigned short pe[4];
            #pragma unroll
            for (int i = 0; i < 4; i++) {
                float p = __expf(sv[t][i] - m_new);
                psum += p;
                pe[i] = f2bf(p);
            }
            ushort4 pw; pw.x = pe[0]; pw.y = pe[1]; pw.z = pe[2]; pw.w = pe[3];
            *(ushort4*)(&pl[w][qi][t * 16 + g * 4]) = pw;   // P[q][mlocal]
        }
        psum += __shfl_xor(psum, 16);
        psum += __shfl_xor(psum, 32);
        l_run = l_run * alpha + psum;
        m_run = m_new;

        // per-output-row alpha (rows q = g*4+i in O acc layout)
        float aL[4];
        #pragma unroll
        for (int i = 0; i < 4; i++) aL[i] = __shfl(alpha, g * 4 + i);

        __builtin_amdgcn_sched_barrier(0);
        // PV: A-frag P[row=qi][k = g*8+j] from LDS; B-frag Mem[m][d] from mt
        bf16x8 pa = *(const bf16x8*)(&pl[w][qi][g * 8]);
        #pragma unroll
        for (int d2 = 0; d2 < 8; d2++) {
            bf16x8 vf = *(const bf16x8*)(mtB + (size_t)(d2 * 16 + qi) * MM + m0 + g * 8);
            f32x4 oo = o[d2];
            #pragma unroll
            for (int i = 0; i < 4; i++) oo[i] *= aL[i];
            o[d2] = __builtin_amdgcn_mfma_f32_16x16x32_bf16(pa, vf, oo, 0, 0, 0);
        }
    }

    // ---- in-block merge of the NSPLIT partial states ----
    if (g == 0) { mlb[w][qi][0] = m_run; mlb[w][qi][1] = l_run; }
    __syncthreads();

    // scale own O rows by exp(m_w - M_glob) and dump to LDS
    #pragma unroll
    for (int i = 0; i < 4; i++) {
        int row = g * 4 + i;
        float M = fmaxf(fmaxf(mlb[0][row][0], mlb[1][row][0]),
                        fmaxf(mlb[2][row][0], mlb[3][row][0]));
        float wsc = __expf(mlb[w][row][0] - M);
        #pragma unroll
        for (int d2 = 0; d2 < 8; d2++)
            Obuf[w][row][d2 * 16 + qi] = o[d2][i] * wsc;
    }
    __syncthreads();

    // reduce: thread t -> row = t>>4, d0 = (t&15)*8
    int row = tid >> 4, d0 = (tid & 15) * 8;
    float M = fmaxf(fmaxf(mlb[0][row][0], mlb[1][row][0]),
                    fmaxf(mlb[2][row][0], mlb[3][row][0]));
    float lg = 0.f;
    #pragma unroll
    for (int w2 = 0; w2 < NSPLIT; w2++)
        lg += __expf(mlb[w2][row][0] - M) * mlb[w2][row][1];
    float invl = 1.f / lg;
    float acc[8];
    #pragma unroll
    for (int j = 0; j < 8; j++)
        acc[j] = ((Obuf[0][row][d0 + j] + Obuf[1][row][d0 + j]) +
                  (Obuf[2][row][d0 + j] + Obuf[3][row][d0 + j])) * invl;
    float4* dst = (float4*)(out1 + ((size_t)b * NN + n0 + row) * DD + d0);
    dst[0] = (float4){acc[0], acc[1], acc[2], acc[3]};
    dst[1] = (float4){acc[4], acc[5], acc[6], acc[7]};
    if (d0 == 0) rowmax[b * NN + n0 + row] = M;
}

// ---- m2q partials: block = (b, chunk of 128 n-rows) ----
__global__ __launch_bounds__(256) void m2q_partial(
    const float* __restrict__ rowmax, const float* __restrict__ query,
    float* __restrict__ partial, float* __restrict__ Zbuf)
{
    int bid = blockIdx.x;
    int b = bid >> 3, ch = bid & 7;
    int tid = threadIdx.x, lane = tid & 63, wv = tid >> 6;
    __shared__ float red[8];
    __shared__ float pe[128];
    __shared__ float acc1[128];

    float4 rv = *(const float4*)(rowmax + b * NN + tid * 4);
    float mx = fmaxf(fmaxf(rv.x, rv.y), fmaxf(rv.z, rv.w));
    #pragma unroll
    for (int o = 32; o; o >>= 1) mx = fmaxf(mx, __shfl_xor(mx, o));
    if (lane == 0) red[wv] = mx;
    __syncthreads();
    mx = fmaxf(fmaxf(red[0], red[1]), fmaxf(red[2], red[3]));
    float ls = __expf(rv.x - mx) + __expf(rv.y - mx) + __expf(rv.z - mx) + __expf(rv.w - mx);
    #pragma unroll
    for (int o = 32; o; o >>= 1) ls += __shfl_xor(ls, o);
    if (lane == 0) red[4 + wv] = ls;
    if (tid < 128) pe[tid] = __expf(rowmax[b * NN + ch * 128 + tid] - mx);
    __syncthreads();
    float Z = (red[4] + red[5]) + (red[6] + red[7]);

    int d = tid & 127, h = tid >> 7;
    const float* qb = query + ((size_t)b * NN + ch * 128 + h * 64) * DD + d;
    float acc = 0.f;
    #pragma unroll 8
    for (int n = 0; n < 64; n++) acc += pe[h * 64 + n] * qb[(size_t)n * DD];
    if (h) acc1[d] = acc;
    __syncthreads();
    if (!h) partial[(b * 8 + ch) * DD + d] = acc + acc1[d];
    if (tid == 0) Zbuf[b] = Z;
}

// ---- m2q final combine ----
__global__ void m2q_final(const float* __restrict__ partial, const float* __restrict__ Zbuf,
                          float* __restrict__ m2q)
{
    int b = blockIdx.x, d = threadIdx.x;
    float s = 0.f;
    #pragma unroll
    for (int ch = 0; ch < 8; ch++) s += partial[(b * 8 + ch) * DD + d];
    m2q[b * DD + d] = s / Zbuf[b];
}

// ---- broadcast m2q to out2[b][n][d] ----
__global__ void bcast_kernel(const float* __restrict__ m2q, float4* __restrict__ out2)
{
    int i = blockIdx.x * 256 + threadIdx.x;   // 524288 float4s
    int b = i >> 15;                          // N*D/4 = 32768
    int d4 = i & 31;                          // D/4 = 32
    out2[i] = ((const float4*)m2q)[(b << 5) + d4];
}

extern "C" void kernel_launch(void* const* d_in, const int* in_sizes, int n_in,
                              void* d_out, int out_size, void* d_ws, size_t ws_size,
                              hipStream_t stream)
{
    const float* query  = (const float*)d_in[0];
    const float* memory = (const float*)d_in[1];
    const float* w_q    = (const float*)d_in[2];
    const float* w_m    = (const float*)d_in[3];
    const float* w_qm   = (const float*)d_in[4];
    const int*   qmask  = (const int*)d_in[5];
    const int*   mmask  = (const int*)d_in[6];
    float* out1 = (float*)d_out;
    float* out2 = out1 + (size_t)BB * NN * DD;

    char* ws = (char*)d_ws;
    float* a       = (float*)ws;                 // B*N
    float* c       = a + BB * NN;                // B*M
    float* rowmax  = c + BB * MM;                // B*N
    float* m2q     = rowmax + BB * NN;           // B*D
    float* partial = m2q + BB * DD;              // B*8*D
    float* Zbuf    = partial + BB * 8 * DD;      // B
    unsigned short* qp = (unsigned short*)(ws + (1 << 20));
    unsigned short* mb = qp + (size_t)BB * NN * DD;
    unsigned short* mt = mb + (size_t)BB * MM * DD;

    prep_rows<<<dim3((BB * NN + BB * MM) / 4), 256, 0, stream>>>(query, memory, w_q, w_m, w_qm, a, c, qp, mb);
    transpose_mem<<<dim3(BB * (MM / 64) * (DD / 64)), 256, 0, stream>>>(memory, mt);
    flash_fwd<<<dim3(BB * 64), 256, 0, stream>>>(qp, mb, mt, a, c, qmask, mmask, out1, rowmax);
    m2q_partial<<<dim3(BB * 8), 256, 0, stream>>>(rowmax, query, partial, Zbuf);
    m2q_final<<<dim3(BB), 128, 0, stream>>>(partial, Zbuf, m2q);
    bcast_kernel<<<dim3(2048), 256, 0, stream>>>(m2q, (float4*)out2);
}